// Round 6
// baseline (140.739 us; speedup 1.0000x reference)
//
#include <hip/hip_runtime.h>
#include <hip/hip_bf16.h>

// out = (Q K^T) V * scale, softmax discarded => associativity:
//   out_i = Q_i @ (K_i^T @ V_i) * scale over 32 blocks of 2048 flat rows of
//   the (65536,64) view of the (4096,1024) projections.
// R16: R15 resubmit with P-chunk indexing FIXED. Flat row FR = grow*16+head,
// attention block = FR>>11 = grow>>7 = blockIdx.x (NOT batch*16+head).
// Chunk = by*2+h (the 16 (by,h) head-pairs partition the block's 2048 rows).
// Fusion: one block does K-loop (park K bf16 in 32 VGPRs) -> V-loop (same
// LDS) -> in-block kT (restage K,V transposed+swizzled, 16 MFMA/wave/head)
// -> write P chunk. K/V never touch HBM; kT kernel deleted.
// 3 kernels: cvt -> qkv_kt_fused (32,8,2: z=0 KV, z=1 Q) -> qT_fused
// (verbatim R14-passing: redundant P-reduce prologue + K=64 mini-GEMM).

#define E_DIM 1024
#define N_ROWS 4096

typedef __attribute__((ext_vector_type(8))) short bf16x8;
typedef __attribute__((ext_vector_type(4))) float f32x4;

// ---- ws layout ----
// shorts: QB 0 (Q bf16, 8.4MB)  XB 12582912  WB 16777216
// floats: P 9961472 (32 blk x 16 chunks x 4096, [d][e]) = 8 MB
#define QB_U 0
#define XB_U 12582912
#define WB_U 16777216
#define P_F  9961472

__device__ __forceinline__ unsigned short f2b(float f) {
    union { float f; unsigned int i; } c; c.f = f;
    unsigned int r = c.i + 0x7FFFu + ((c.i >> 16) & 1u);   // RNE (finite data)
    return (unsigned short)(r >> 16);
}

__device__ __forceinline__ uint4 pack8(const f32x4 a, const f32x4 b) {
    uint4 o;
    o.x = (unsigned)f2b(a[0]) | ((unsigned)f2b(a[1]) << 16);
    o.y = (unsigned)f2b(a[2]) | ((unsigned)f2b(a[3]) << 16);
    o.z = (unsigned)f2b(b[0]) | ((unsigned)f2b(b[1]) << 16);
    o.w = (unsigned)f2b(b[2]) | ((unsigned)f2b(b[3]) << 16);
    return o;
}

typedef __attribute__((address_space(1))) const void* gptr_t;
typedef __attribute__((address_space(3))) void* lptr_t;
__device__ __forceinline__ void gl_lds16(const void* g, void* l) {
    __builtin_amdgcn_global_load_lds((gptr_t)g, (lptr_t)l, 16, 0, 0);
}

// swizzled index into a [row][64] LDS tile (8 slots of 8 elems per row)
__device__ __forceinline__ int sw_idx(int row, int r) {
    return row * 64 + (((((r) >> 3) & 7) ^ (row & 7)) << 3) + (r & 7);
}

// swizzled index into a [row][128] LDS tile (16 slots of 8; XOR low 3 slot bits)
__device__ __forceinline__ int sw128(int row, int r) {
    return row * 128 + ((((r >> 3) ^ (row & 7)) & 15) << 3) + (r & 7);
}

// ---------------------------------------------------------------------------
// Kernel 0: fp32 -> bf16 convert: x (4 MB-segs) + Wq/Wk/Wv.
// ---------------------------------------------------------------------------
__global__ __launch_bounds__(256) void cvt_bf16(
    const float* __restrict__ x,  const float* __restrict__ wq,
    const float* __restrict__ wk, const float* __restrict__ wv,
    unsigned short* __restrict__ dst0)
{
    const int seg = blockIdx.y;
    const float* __restrict__ src;
    unsigned short* __restrict__ dst;
    if (seg < 4) { src = x + (size_t)seg * 1048576; dst = dst0 + (size_t)seg * 1048576; }
    else {
        src = (seg == 4) ? wq : (seg == 5) ? wk : wv;
        dst = dst0 + 4194304 + (size_t)(seg - 4) * 1048576;
    }
    const int i = blockIdx.x * 256 + threadIdx.x;   // 0..131071
    const float4 a = *(const float4*)(src + (size_t)i * 8);
    const float4 b = *(const float4*)(src + (size_t)i * 8 + 4);
    uint4 o;
    o.x = (unsigned)f2b(a.x) | ((unsigned)f2b(a.y) << 16);
    o.y = (unsigned)f2b(a.z) | ((unsigned)f2b(a.w) << 16);
    o.z = (unsigned)f2b(b.x) | ((unsigned)f2b(b.y) << 16);
    o.w = (unsigned)f2b(b.z) | ((unsigned)f2b(b.w) << 16);
    *(uint4*)(dst + (size_t)i * 8) = o;
}

// ---------------------------------------------------------------------------
// One full 128x128 K=1024 GEMM accumulation loop (R10 body). acc += Xb@W^T.
// Als/Bls: [128][64] XOR-swizzled staging tiles (16 KB each).
// ---------------------------------------------------------------------------
__device__ __forceinline__ void gemm_loop(
    const unsigned short* __restrict__ Xb, const unsigned short* __restrict__ W,
    unsigned short* Als, unsigned short* Bls,
    int m0, int n0, int w, int lane, f32x4 (&acc)[4][4])
{
    const int quad = lane >> 4;
    const int fm   = lane & 15;
    const int sw8  = fm & 7;
    const int srow = lane >> 3;                       // 0..7
    const int skc  = ((lane & 7) ^ (lane >> 3)) * 8;  // swizzled global chunk
    const int wm = (w >> 1) * 64;
    const int wn = (w & 1) * 64;

    for (int k0 = 0; k0 < E_DIM; k0 += 64) {
        #pragma unroll
        for (int c = 0; c < 4; ++c) {
            const int r = w * 32 + c * 8;
            gl_lds16((const void*)(Xb + (size_t)(m0 + r + srow) * E_DIM + k0 + skc),
                     (void*)((char*)Als + r * 128 + lane * 16));
            gl_lds16((const void*)(W + (size_t)(n0 + r + srow) * E_DIM + k0 + skc),
                     (void*)((char*)Bls + r * 128 + lane * 16));
        }
        __syncthreads();

        #pragma unroll
        for (int kk = 0; kk < 2; ++kk) {
            const int slot = ((kk * 4 + quad) ^ sw8) * 8;
            bf16x8 af[4], bf[4];
            #pragma unroll
            for (int t = 0; t < 4; ++t) {
                af[t] = *(const bf16x8*)(Als + (wm + t * 16 + fm) * 64 + slot);
                bf[t] = *(const bf16x8*)(Bls + (wn + t * 16 + fm) * 64 + slot);
            }
            #pragma unroll
            for (int rt = 0; rt < 4; ++rt)
                #pragma unroll
                for (int ct = 0; ct < 4; ++ct)
                    acc[rt][ct] = __builtin_amdgcn_mfma_f32_16x16x32_bf16(
                        af[rt], bf[ct], acc[rt][ct], 0, 0, 0);
        }
        __syncthreads();
    }
}

// ---------------------------------------------------------------------------
// Kernel A (fused): grid (32, 8, 2).
// z=0 (dispatched first, long pole): KV-fused tile. K-loop -> park K bf16 in
//   32 VGPRs -> V-loop (same LDS) -> in-block kT per head: restage K,V
//   transposed+swizzled into dead staging LDS ([64 e][128 r]), 16 MFMA/wave,
//   write P[bx][by*2+h][d][e] f32. K/V never written to global.
// z=1: Q tile (R10 body) -> Q bf16 at QB.
// ---------------------------------------------------------------------------
__global__ __launch_bounds__(256, 3) void qkv_kt_fused(
    const unsigned short* __restrict__ Xb,
    const unsigned short* __restrict__ Wb,
    const float* __restrict__ bq, const float* __restrict__ bk,
    const float* __restrict__ bv,
    unsigned short* __restrict__ qkv,
    float* __restrict__ P)
{
    __shared__ __align__(16) unsigned short S[16384];   // 32 KB

    const int tid  = threadIdx.x;
    const int w    = tid >> 6;
    const int lane = tid & 63;
    const int quad = lane >> 4;
    const int fm   = lane & 15;
    const int sw8  = fm & 7;
    const int rbase = quad * 4;
    const int m0 = blockIdx.x * 128;
    const int n0 = blockIdx.y * 128;
    const int wm = (w >> 1) * 64;
    const int wn = (w & 1) * 64;

    f32x4 acc[4][4];
    #pragma unroll
    for (int i = 0; i < 4; ++i)
        #pragma unroll
        for (int j = 0; j < 4; ++j)
            acc[i][j] = f32x4{0.f, 0.f, 0.f, 0.f};

    if (blockIdx.z == 1) {
        // ---------------- Q path (R10 body) ----------------
        gemm_loop(Xb, Wb, S, S + 8192, m0, n0, w, lane, acc);

        float bcol[4];
        #pragma unroll
        for (int ct = 0; ct < 4; ++ct) bcol[ct] = bq[n0 + wn + ct * 16 + fm];

        #pragma unroll
        for (int rt = 0; rt < 4; ++rt) {
            #pragma unroll
            for (int ct = 0; ct < 4; ++ct) {
                #pragma unroll
                for (int r = 0; r < 4; ++r) {
                    const int row = m0 + wm + rt * 16 + rbase + r;
                    const int col = n0 + wn + ct * 16 + fm;
                    qkv[(size_t)row * E_DIM + col] = f2b(acc[rt][ct][r] + bcol[ct]);
                }
            }
        }
        return;
    }

    // ---------------- KV path ----------------
    // K projection
    gemm_loop(Xb, Wb + 1048576, S, S + 8192, m0, n0, w, lane, acc);

    float bcK[4];
    #pragma unroll
    for (int ct = 0; ct < 4; ++ct) bcK[ct] = bk[n0 + wn + ct * 16 + fm];

    // park K-tile as packed bf16 (rows rbase..rbase+3 per frag -> uint2)
    uint2 pk[4][4];
    #pragma unroll
    for (int rt = 0; rt < 4; ++rt)
        #pragma unroll
        for (int ct = 0; ct < 4; ++ct) {
            uint2 v;
            v.x = (unsigned)f2b(acc[rt][ct][0] + bcK[ct])
                | ((unsigned)f2b(acc[rt][ct][1] + bcK[ct]) << 16);
            v.y = (unsigned)f2b(acc[rt][ct][2] + bcK[ct])
                | ((unsigned)f2b(acc[rt][ct][3] + bcK[ct]) << 16);
            pk[rt][ct] = v;
        }

    // V projection (re-zero acc, reuse LDS)
    #pragma unroll
    for (int i = 0; i < 4; ++i)
        #pragma unroll
        for (int j = 0; j < 4; ++j)
            acc[i][j] = f32x4{0.f, 0.f, 0.f, 0.f};
    gemm_loop(Xb, Wb + 2097152, S, S + 8192, m0, n0, w, lane, acc);

    float bcV[4];
    #pragma unroll
    for (int ct = 0; ct < 4; ++ct) bcV[ct] = bv[n0 + wn + ct * 16 + fm];

    // in-block kT: one head at a time. Kt/Vt [64 e][128 r] swizzled, 16 KB each.
    unsigned short* Kt = S;
    unsigned short* Vt = S + 8192;

    #pragma unroll
    for (int h = 0; h < 2; ++h) {
        __syncthreads();   // staging/previous-head reads done before overwrite
        if ((w & 1) == h) {
            // this wave's 64 cols ARE head h (wn = h*64): write K,V transposed
            #pragma unroll
            for (int rt = 0; rt < 4; ++rt)
                #pragma unroll
                for (int ct = 0; ct < 4; ++ct) {
                    const int e  = ct * 16 + fm;              // local col 0..63
                    const int r0 = wm + rt * 16 + rbase;      // local row, %4==0
                    *(uint2*)(Kt + sw128(e, r0)) = pk[rt][ct];
                    uint2 pv;
                    pv.x = (unsigned)f2b(acc[rt][ct][0] + bcV[ct])
                         | ((unsigned)f2b(acc[rt][ct][1] + bcV[ct]) << 16);
                    pv.y = (unsigned)f2b(acc[rt][ct][2] + bcV[ct])
                         | ((unsigned)f2b(acc[rt][ct][3] + bcV[ct]) << 16);
                    *(uint2*)(Vt + sw128(e, r0)) = pv;
                }
        }
        __syncthreads();

        // Tpart[d][e] = sum_{r<128} V[r][d]*K[r][e]; wave w: d = w*16..+16
        f32x4 t[4];
        #pragma unroll
        for (int nt = 0; nt < 4; ++nt) t[nt] = f32x4{0.f, 0.f, 0.f, 0.f};
        #pragma unroll
        for (int kk = 0; kk < 4; ++kk) {
            const int slot = ((kk * 4 + quad) ^ sw8) << 3;
            const bf16x8 af = *(const bf16x8*)(Vt + (w * 16 + fm) * 128 + slot);
            #pragma unroll
            for (int nt = 0; nt < 4; ++nt) {
                const bf16x8 bf = *(const bf16x8*)(Kt + (nt * 16 + fm) * 128 + slot);
                t[nt] = __builtin_amdgcn_mfma_f32_16x16x32_bf16(af, bf, t[nt], 0, 0, 0);
            }
        }

        // FIXED (R16): attention block = grow>>7 = blockIdx.x; the 16 chunks
        // of block bx are the (by,h) head-pairs (partition; order irrelevant).
        const int ih    = blockIdx.x;
        const int chunk = blockIdx.y * 2 + h;
        float* __restrict__ Pout = P + ((size_t)ih * 16 + chunk) * 4096;
        #pragma unroll
        for (int nt = 0; nt < 4; ++nt)
            #pragma unroll
            for (int r = 0; r < 4; ++r)
                Pout[(size_t)(w * 16 + rbase + r) * 64 + nt * 16 + fm] = t[nt][r];
    }
}

// ---------------------------------------------------------------------------
// Kernel C (verbatim R14-passing): per block b: i = (b&7) + ((b>>3)&3)*8,
// sub = b>>5. Redundant reduce of P[i]'s 16 chunks -> Tls bf16 swizzled,
// Q staged async under it, then out = 0.125 * Qflat @ T^T (K=64 mini-GEMM).
// ---------------------------------------------------------------------------
__global__ __launch_bounds__(256, 2) void qT_fused(
    const unsigned short* __restrict__ qkv,
    const float* __restrict__ P,
    float* __restrict__ out)
{
    __shared__ __align__(16) unsigned short Als[128 * 64];  // 16 KB: Q rows
    __shared__ __align__(16) unsigned short Tls[64 * 64];   //  8 KB: T[d][e]

    const int b    = blockIdx.x;            // 0..511
    const int i    = (b & 7) + ((b >> 3) & 3) * 8;   // attn block
    const int sub  = b >> 5;                          // 0..15
    const int r0   = (i * 16 + sub) * 128;            // flat Q row base
    const int tid  = threadIdx.x;
    const int w    = tid >> 6;
    const int lane = tid & 63;
    const int quad = lane >> 4;
    const int fm   = lane & 15;
    const int sw8  = fm & 7;

    const unsigned short* __restrict__ Qb = qkv + QB_U + (size_t)r0 * 64;

    // issue Q staging first (async via vmcnt; hides under the P reduce)
    const int soff = (lane >> 3) * 64 + (((lane & 7) ^ (lane >> 3)) << 3);
    #pragma unroll
    for (int c = 0; c < 4; ++c)
        gl_lds16((const void*)(Qb + (w * 4 + c) * 512 + soff),
                 (void*)((char*)Als + (w * 4 + c) * 1024));

    // redundant per-block reduce of P[i] (16 chunks) -> Tls bf16 swizzled
    {
        const int d  = tid >> 2;                       // 0..63
        const int e0 = (tid & 3) << 4;                 // 0,16,32,48
        const float* p = P + (size_t)i * 65536 + (size_t)d * 64 + e0;
        f32x4 s0{0.f,0.f,0.f,0.f}, s1{0.f,0.f,0.f,0.f};
        f32x4 s2{0.f,0.f,0.f,0.f}, s3{0.f,0.f,0.f,0.f};
        #pragma unroll
        for (int c = 0; c < 16; ++c) {
            s0 += *(const f32x4*)(p + (size_t)c * 4096);
            s1 += *(const f32x4*)(p + (size_t)c * 4096 + 4);
            s2 += *(const f32x4*)(p + (size_t)c * 4096 + 8);
            s3 += *(const f32x4*)(p + (size_t)c * 4096 + 12);
        }
        const int c0 = e0 >> 3;                        // even slot index
        *(uint4*)(Tls + d * 64 + ((c0 ^ (d & 7)) << 3))       = pack8(s0, s1);
        *(uint4*)(Tls + d * 64 + (((c0 + 1) ^ (d & 7)) << 3)) = pack8(s2, s3);
    }
    __syncthreads();   // drains gl_lds16 (vmcnt) + orders Tls writes

    // qT mini-GEMM
    bf16x8 af[2][2], bf[4][2];
    #pragma unroll
    for (int mt = 0; mt < 2; ++mt)
        #pragma unroll
        for (int kk = 0; kk < 2; ++kk)
            af[mt][kk] = *(const bf16x8*)(Als + (w * 32 + mt * 16 + fm) * 64
                                          + (((kk * 4 + quad) ^ sw8) << 3));
    #pragma unroll
    for (int nt = 0; nt < 4; ++nt)
        #pragma unroll
        for (int kk = 0; kk < 2; ++kk)
            bf[nt][kk] = *(const bf16x8*)(Tls + (nt * 16 + fm) * 64
                                          + (((kk * 4 + quad) ^ sw8) << 3));

    f32x4 acc[2][4];
    #pragma unroll
    for (int mt = 0; mt < 2; ++mt)
        #pragma unroll
        for (int nt = 0; nt < 4; ++nt)
            acc[mt][nt] = f32x4{0.f, 0.f, 0.f, 0.f};

    #pragma unroll
    for (int kk = 0; kk < 2; ++kk)
        #pragma unroll
        for (int mt = 0; mt < 2; ++mt)
            #pragma unroll
            for (int nt = 0; nt < 4; ++nt)
                acc[mt][nt] = __builtin_amdgcn_mfma_f32_16x16x32_bf16(
                    af[mt][kk], bf[nt][kk], acc[mt][nt], 0, 0, 0);

    const int rbase = (lane >> 4) * 4;
    #pragma unroll
    for (int mt = 0; mt < 2; ++mt) {
        #pragma unroll
        for (int nt = 0; nt < 4; ++nt) {
            #pragma unroll
            for (int r = 0; r < 4; ++r) {
                const int row = r0 + w * 32 + mt * 16 + rbase + r;
                const int col = nt * 16 + fm;
                out[(size_t)row * 64 + col] = 0.125f * acc[mt][nt][r];
            }
        }
    }
}

extern "C" void kernel_launch(void* const* d_in, const int* in_sizes, int n_in,
                              void* d_out, int out_size, void* d_ws, size_t ws_size,
                              hipStream_t stream)
{
    const float* x  = (const float*)d_in[0];
    const float* Wq = (const float*)d_in[1];
    const float* bq = (const float*)d_in[2];
    const float* Wk = (const float*)d_in[3];
    const float* bk = (const float*)d_in[4];
    const float* Wv = (const float*)d_in[5];
    const float* bv = (const float*)d_in[6];
    float* wsf = (float*)d_ws;
    unsigned short* wsu = (unsigned short*)d_ws;
    float* out = (float*)d_out;

    dim3 gCvt(512, 7);
    cvt_bf16<<<gCvt, 256, 0, stream>>>(x, Wq, Wk, Wv, wsu + XB_U);

    dim3 gG(N_ROWS / 128, E_DIM / 128, 2);   // 32 x 8 x {KV, Q}
    qkv_kt_fused<<<gG, 256, 0, stream>>>(wsu + XB_U, wsu + WB_U,
                                         bq, bk, bv, wsu, wsf + P_F);

    qT_fused<<<512, 256, 0, stream>>>(wsu, wsf + P_F, out);
}

// Round 7
// 124.949 us; speedup vs baseline: 1.1264x; 1.1264x over previous
//
#include <hip/hip_runtime.h>
#include <hip/hip_bf16.h>

// out = (Q K^T) V * scale, softmax discarded => associativity:
//   out_i = Q_i @ (K_i^T @ V_i) * scale over 32 blocks of 2048 flat rows of
//   the (65536,64) view of the (4096,1024) projections.
// R17: R16's fusion was right, its occupancy was wrong (512 blocks = 2/CU,
// serial K->V loop). Now: KV tile = 128x64 (ONE head), single K-pass staging
// X+Wk+Wv (shared X frags, both accumulators), kT epilogue in-block. Grid is
// 768 near-uniform blocks (512 KV + 256 Q) at 32KB LDS / ~140 VGPR -> 3/CU.
// P[bx][chunk=hy] = head-slice partials (same partition family as R16-passing).
// 3 kernels: cvt -> qkvkt768 -> qT_fused (verbatim passing).

#define E_DIM 1024
#define N_ROWS 4096

typedef __attribute__((ext_vector_type(8))) short bf16x8;
typedef __attribute__((ext_vector_type(4))) float f32x4;

// ---- ws layout ----
// shorts: QB 0 (Q bf16, 8.4MB)  XB 12582912  WB 16777216
// floats: P 9961472 (32 blk x 16 chunks x 4096, [d][e]) = 8 MB
#define QB_U 0
#define XB_U 12582912
#define WB_U 16777216
#define P_F  9961472

__device__ __forceinline__ unsigned short f2b(float f) {
    union { float f; unsigned int i; } c; c.f = f;
    unsigned int r = c.i + 0x7FFFu + ((c.i >> 16) & 1u);   // RNE (finite data)
    return (unsigned short)(r >> 16);
}

__device__ __forceinline__ uint4 pack8(const f32x4 a, const f32x4 b) {
    uint4 o;
    o.x = (unsigned)f2b(a[0]) | ((unsigned)f2b(a[1]) << 16);
    o.y = (unsigned)f2b(a[2]) | ((unsigned)f2b(a[3]) << 16);
    o.z = (unsigned)f2b(b[0]) | ((unsigned)f2b(b[1]) << 16);
    o.w = (unsigned)f2b(b[2]) | ((unsigned)f2b(b[3]) << 16);
    return o;
}

// pack 4 acc rows + bias into 4 bf16 (one uint2)
__device__ __forceinline__ uint2 packfrag(const f32x4 a, float b) {
    uint2 v;
    v.x = (unsigned)f2b(a[0] + b) | ((unsigned)f2b(a[1] + b) << 16);
    v.y = (unsigned)f2b(a[2] + b) | ((unsigned)f2b(a[3] + b) << 16);
    return v;
}

typedef __attribute__((address_space(1))) const void* gptr_t;
typedef __attribute__((address_space(3))) void* lptr_t;
__device__ __forceinline__ void gl_lds16(const void* g, void* l) {
    __builtin_amdgcn_global_load_lds((gptr_t)g, (lptr_t)l, 16, 0, 0);
}

// swizzled index into a [row][64] LDS tile (8 slots of 8 elems per row)
__device__ __forceinline__ int sw_idx(int row, int r) {
    return row * 64 + (((((r) >> 3) & 7) ^ (row & 7)) << 3) + (r & 7);
}

// swizzled index into a [row][128] LDS tile (16 slots of 8; XOR low 3 slot bits)
__device__ __forceinline__ int sw128(int row, int r) {
    return row * 128 + ((((r >> 3) ^ (row & 7)) & 15) << 3) + (r & 7);
}

// ---------------------------------------------------------------------------
// Kernel 0: fp32 -> bf16 convert: x (4 MB-segs) + Wq/Wk/Wv.
// ---------------------------------------------------------------------------
__global__ __launch_bounds__(256) void cvt_bf16(
    const float* __restrict__ x,  const float* __restrict__ wq,
    const float* __restrict__ wk, const float* __restrict__ wv,
    unsigned short* __restrict__ dst0)
{
    const int seg = blockIdx.y;
    const float* __restrict__ src;
    unsigned short* __restrict__ dst;
    if (seg < 4) { src = x + (size_t)seg * 1048576; dst = dst0 + (size_t)seg * 1048576; }
    else {
        src = (seg == 4) ? wq : (seg == 5) ? wk : wv;
        dst = dst0 + 4194304 + (size_t)(seg - 4) * 1048576;
    }
    const int i = blockIdx.x * 256 + threadIdx.x;   // 0..131071
    const float4 a = *(const float4*)(src + (size_t)i * 8);
    const float4 b = *(const float4*)(src + (size_t)i * 8 + 4);
    uint4 o;
    o.x = (unsigned)f2b(a.x) | ((unsigned)f2b(a.y) << 16);
    o.y = (unsigned)f2b(a.z) | ((unsigned)f2b(a.w) << 16);
    o.z = (unsigned)f2b(b.x) | ((unsigned)f2b(b.y) << 16);
    o.w = (unsigned)f2b(b.z) | ((unsigned)f2b(b.w) << 16);
    *(uint4*)(dst + (size_t)i * 8) = o;
}

// ---------------------------------------------------------------------------
// One full 128x128 K=1024 GEMM accumulation loop (R10 body). acc += Xb@W^T.
// ---------------------------------------------------------------------------
__device__ __forceinline__ void gemm_loop(
    const unsigned short* __restrict__ Xb, const unsigned short* __restrict__ W,
    unsigned short* Als, unsigned short* Bls,
    int m0, int n0, int w, int lane, f32x4 (&acc)[4][4])
{
    const int quad = lane >> 4;
    const int fm   = lane & 15;
    const int sw8  = fm & 7;
    const int srow = lane >> 3;                       // 0..7
    const int skc  = ((lane & 7) ^ (lane >> 3)) * 8;  // swizzled global chunk
    const int wm = (w >> 1) * 64;
    const int wn = (w & 1) * 64;

    for (int k0 = 0; k0 < E_DIM; k0 += 64) {
        #pragma unroll
        for (int c = 0; c < 4; ++c) {
            const int r = w * 32 + c * 8;
            gl_lds16((const void*)(Xb + (size_t)(m0 + r + srow) * E_DIM + k0 + skc),
                     (void*)((char*)Als + r * 128 + lane * 16));
            gl_lds16((const void*)(W + (size_t)(n0 + r + srow) * E_DIM + k0 + skc),
                     (void*)((char*)Bls + r * 128 + lane * 16));
        }
        __syncthreads();

        #pragma unroll
        for (int kk = 0; kk < 2; ++kk) {
            const int slot = ((kk * 4 + quad) ^ sw8) * 8;
            bf16x8 af[4], bf[4];
            #pragma unroll
            for (int t = 0; t < 4; ++t) {
                af[t] = *(const bf16x8*)(Als + (wm + t * 16 + fm) * 64 + slot);
                bf[t] = *(const bf16x8*)(Bls + (wn + t * 16 + fm) * 64 + slot);
            }
            #pragma unroll
            for (int rt = 0; rt < 4; ++rt)
                #pragma unroll
                for (int ct = 0; ct < 4; ++ct)
                    acc[rt][ct] = __builtin_amdgcn_mfma_f32_16x16x32_bf16(
                        af[rt], bf[ct], acc[rt][ct], 0, 0, 0);
        }
        __syncthreads();
    }
}

// ---------------------------------------------------------------------------
// Kernel A: flat grid of 768 blocks.
// b < 512: KV block (bx=b>>4 row-chunk, hy=b&15 head). One K-pass stages
//   X[128][64] + Wk[64][64] + Wv[64][64]; shared X frags feed both acck and
//   accv (32 MFMA/K-step, same as a Q block). Epilogue: transpose-restage
//   K,V (+bias, bf16) into [64][128] swizzled LDS, 16 MFMA/wave kT,
//   write P[bx][hy][d][e]. K/V never touch HBM.
// b >= 512: Q block (idx=b-512: m0=(idx&31)*128, n0=(idx>>5)*128), R10 body.
// ---------------------------------------------------------------------------
__global__ __launch_bounds__(256, 3) void qkvkt768(
    const unsigned short* __restrict__ Xb,
    const unsigned short* __restrict__ Wb,
    const float* __restrict__ bq, const float* __restrict__ bk,
    const float* __restrict__ bv,
    unsigned short* __restrict__ qkv,
    float* __restrict__ P)
{
    __shared__ __align__(16) unsigned short S[16384];   // 32 KB

    const int b    = blockIdx.x;
    const int tid  = threadIdx.x;
    const int w    = tid >> 6;
    const int lane = tid & 63;
    const int quad = lane >> 4;
    const int fm   = lane & 15;
    const int sw8  = fm & 7;
    const int rbase = quad * 4;
    const int srow = lane >> 3;
    const int skc  = ((lane & 7) ^ (lane >> 3)) * 8;

    if (b >= 512) {
        // ---------------- Q path (R10 body) ----------------
        const int idx = b - 512;
        const int m0 = (idx & 31) * 128;
        const int n0 = (idx >> 5) * 128;
        const int wm = (w >> 1) * 64;
        const int wn = (w & 1) * 64;

        f32x4 acc[4][4];
        #pragma unroll
        for (int i = 0; i < 4; ++i)
            #pragma unroll
            for (int j = 0; j < 4; ++j)
                acc[i][j] = f32x4{0.f, 0.f, 0.f, 0.f};

        gemm_loop(Xb, Wb, S, S + 8192, m0, n0, w, lane, acc);

        float bcol[4];
        #pragma unroll
        for (int ct = 0; ct < 4; ++ct) bcol[ct] = bq[n0 + wn + ct * 16 + fm];

        #pragma unroll
        for (int rt = 0; rt < 4; ++rt) {
            #pragma unroll
            for (int ct = 0; ct < 4; ++ct) {
                #pragma unroll
                for (int r = 0; r < 4; ++r) {
                    const int row = m0 + wm + rt * 16 + rbase + r;
                    const int col = n0 + wn + ct * 16 + fm;
                    qkv[(size_t)row * E_DIM + col] = f2b(acc[rt][ct][r] + bcol[ct]);
                }
            }
        }
        return;
    }

    // ---------------- KV path: 128 rows x 64 cols (one head) ----------------
    const int bx = b >> 4;               // row chunk 0..31
    const int hy = b & 15;               // head 0..15
    const int m0 = bx * 128;
    const int n0 = hy * 64;
    const unsigned short* __restrict__ WK = Wb + 1048576;
    const unsigned short* __restrict__ WV = Wb + 2097152;

    unsigned short* Xls = S;             // [128][64] swizzled, 16 KB
    unsigned short* Kls = S + 8192;      // [64][64]  swizzled,  8 KB
    unsigned short* Vls = S + 12288;     // [64][64]  swizzled,  8 KB

    const int wm = w * 32;               // wave's 32 X-rows

    f32x4 acck[2][4], accv[2][4];
    #pragma unroll
    for (int t = 0; t < 2; ++t)
        #pragma unroll
        for (int n = 0; n < 4; ++n) {
            acck[t][n] = f32x4{0.f, 0.f, 0.f, 0.f};
            accv[t][n] = f32x4{0.f, 0.f, 0.f, 0.f};
        }

    for (int k0 = 0; k0 < E_DIM; k0 += 64) {
        #pragma unroll
        for (int c = 0; c < 4; ++c) {
            const int r = w * 32 + c * 8;
            gl_lds16((const void*)(Xb + (size_t)(m0 + r + srow) * E_DIM + k0 + skc),
                     (void*)((char*)Xls + r * 128 + lane * 16));
        }
        #pragma unroll
        for (int c = 0; c < 2; ++c) {
            const int r = w * 16 + c * 8;
            gl_lds16((const void*)(WK + (size_t)(n0 + r + srow) * E_DIM + k0 + skc),
                     (void*)((char*)Kls + r * 128 + lane * 16));
            gl_lds16((const void*)(WV + (size_t)(n0 + r + srow) * E_DIM + k0 + skc),
                     (void*)((char*)Vls + r * 128 + lane * 16));
        }
        __syncthreads();

        #pragma unroll
        for (int kk = 0; kk < 2; ++kk) {
            const int slot = ((kk * 4 + quad) ^ sw8) * 8;
            bf16x8 af[2], bk_[4], bv_[4];
            #pragma unroll
            for (int t = 0; t < 2; ++t)
                af[t] = *(const bf16x8*)(Xls + (wm + t * 16 + fm) * 64 + slot);
            #pragma unroll
            for (int n = 0; n < 4; ++n) {
                bk_[n] = *(const bf16x8*)(Kls + (n * 16 + fm) * 64 + slot);
                bv_[n] = *(const bf16x8*)(Vls + (n * 16 + fm) * 64 + slot);
            }
            #pragma unroll
            for (int t = 0; t < 2; ++t)
                #pragma unroll
                for (int n = 0; n < 4; ++n) {
                    acck[t][n] = __builtin_amdgcn_mfma_f32_16x16x32_bf16(
                        af[t], bk_[n], acck[t][n], 0, 0, 0);
                    accv[t][n] = __builtin_amdgcn_mfma_f32_16x16x32_bf16(
                        af[t], bv_[n], accv[t][n], 0, 0, 0);
                }
        }
        __syncthreads();
    }

    float bcK[4], bcV[4];
    #pragma unroll
    for (int n = 0; n < 4; ++n) {
        bcK[n] = bk[n0 + n * 16 + fm];
        bcV[n] = bv[n0 + n * 16 + fm];
    }

    // ---- kT epilogue: restage K,V transposed+swizzled into S (free now) ----
    unsigned short* Kt = S;              // [64 e][128 r] swizzled, 16 KB
    unsigned short* Vt = S + 8192;       // [64 d][128 r] swizzled, 16 KB

    #pragma unroll
    for (int t = 0; t < 2; ++t)
        #pragma unroll
        for (int n = 0; n < 4; ++n) {
            const int e  = n * 16 + fm;               // local col 0..63
            const int r0 = wm + t * 16 + rbase;       // local row, %4==0
            *(uint2*)(Kt + sw128(e, r0)) = packfrag(acck[t][n], bcK[n]);
            *(uint2*)(Vt + sw128(e, r0)) = packfrag(accv[t][n], bcV[n]);
        }
    __syncthreads();

    // Tpart[d][e] = sum_{r<128} V[r][d]*K[r][e]; wave w: d = w*16..+16
    f32x4 tacc[4];
    #pragma unroll
    for (int n = 0; n < 4; ++n) tacc[n] = f32x4{0.f, 0.f, 0.f, 0.f};
    #pragma unroll
    for (int kk = 0; kk < 4; ++kk) {
        const int slot = (((kk * 4 + quad) ^ sw8) & 15) << 3;
        const bf16x8 af = *(const bf16x8*)(Vt + (w * 16 + fm) * 128 + slot);
        #pragma unroll
        for (int n = 0; n < 4; ++n) {
            const bf16x8 bf = *(const bf16x8*)(Kt + (n * 16 + fm) * 128 + slot);
            tacc[n] = __builtin_amdgcn_mfma_f32_16x16x32_bf16(af, bf, tacc[n], 0, 0, 0);
        }
    }

    float* __restrict__ Pout = P + ((size_t)bx * 16 + hy) * 4096;
    #pragma unroll
    for (int n = 0; n < 4; ++n)
        #pragma unroll
        for (int r = 0; r < 4; ++r)
            Pout[(size_t)(w * 16 + rbase + r) * 64 + n * 16 + fm] = tacc[n][r];
}

// ---------------------------------------------------------------------------
// Kernel C (verbatim passing): per block b: i = (b&7) + ((b>>3)&3)*8,
// sub = b>>5. Redundant reduce of P[i]'s 16 chunks -> Tls bf16 swizzled,
// Q staged async under it, then out = 0.125 * Qflat @ T^T (K=64 mini-GEMM).
// ---------------------------------------------------------------------------
__global__ __launch_bounds__(256, 2) void qT_fused(
    const unsigned short* __restrict__ qkv,
    const float* __restrict__ P,
    float* __restrict__ out)
{
    __shared__ __align__(16) unsigned short Als[128 * 64];  // 16 KB: Q rows
    __shared__ __align__(16) unsigned short Tls[64 * 64];   //  8 KB: T[d][e]

    const int b    = blockIdx.x;            // 0..511
    const int i    = (b & 7) + ((b >> 3) & 3) * 8;   // attn block
    const int sub  = b >> 5;                          // 0..15
    const int r0   = (i * 16 + sub) * 128;            // flat Q row base
    const int tid  = threadIdx.x;
    const int w    = tid >> 6;
    const int lane = tid & 63;
    const int quad = lane >> 4;
    const int fm   = lane & 15;
    const int sw8  = fm & 7;

    const unsigned short* __restrict__ Qb = qkv + QB_U + (size_t)r0 * 64;

    // issue Q staging first (async via vmcnt; hides under the P reduce)
    const int soff = (lane >> 3) * 64 + (((lane & 7) ^ (lane >> 3)) << 3);
    #pragma unroll
    for (int c = 0; c < 4; ++c)
        gl_lds16((const void*)(Qb + (w * 4 + c) * 512 + soff),
                 (void*)((char*)Als + (w * 4 + c) * 1024));

    // redundant per-block reduce of P[i] (16 chunks) -> Tls bf16 swizzled
    {
        const int d  = tid >> 2;                       // 0..63
        const int e0 = (tid & 3) << 4;                 // 0,16,32,48
        const float* p = P + (size_t)i * 65536 + (size_t)d * 64 + e0;
        f32x4 s0{0.f,0.f,0.f,0.f}, s1{0.f,0.f,0.f,0.f};
        f32x4 s2{0.f,0.f,0.f,0.f}, s3{0.f,0.f,0.f,0.f};
        #pragma unroll
        for (int c = 0; c < 16; ++c) {
            s0 += *(const f32x4*)(p + (size_t)c * 4096);
            s1 += *(const f32x4*)(p + (size_t)c * 4096 + 4);
            s2 += *(const f32x4*)(p + (size_t)c * 4096 + 8);
            s3 += *(const f32x4*)(p + (size_t)c * 4096 + 12);
        }
        const int c0 = e0 >> 3;                        // even slot index
        *(uint4*)(Tls + d * 64 + ((c0 ^ (d & 7)) << 3))       = pack8(s0, s1);
        *(uint4*)(Tls + d * 64 + (((c0 + 1) ^ (d & 7)) << 3)) = pack8(s2, s3);
    }
    __syncthreads();   // drains gl_lds16 (vmcnt) + orders Tls writes

    // qT mini-GEMM
    bf16x8 af[2][2], bf[4][2];
    #pragma unroll
    for (int mt = 0; mt < 2; ++mt)
        #pragma unroll
        for (int kk = 0; kk < 2; ++kk)
            af[mt][kk] = *(const bf16x8*)(Als + (w * 32 + mt * 16 + fm) * 64
                                          + (((kk * 4 + quad) ^ sw8) << 3));
    #pragma unroll
    for (int nt = 0; nt < 4; ++nt)
        #pragma unroll
        for (int kk = 0; kk < 2; ++kk)
            bf[nt][kk] = *(const bf16x8*)(Tls + (nt * 16 + fm) * 64
                                          + (((kk * 4 + quad) ^ sw8) << 3));

    f32x4 acc[2][4];
    #pragma unroll
    for (int mt = 0; mt < 2; ++mt)
        #pragma unroll
        for (int nt = 0; nt < 4; ++nt)
            acc[mt][nt] = f32x4{0.f, 0.f, 0.f, 0.f};

    #pragma unroll
    for (int kk = 0; kk < 2; ++kk)
        #pragma unroll
        for (int mt = 0; mt < 2; ++mt)
            #pragma unroll
            for (int nt = 0; nt < 4; ++nt)
                acc[mt][nt] = __builtin_amdgcn_mfma_f32_16x16x32_bf16(
                    af[mt][kk], bf[nt][kk], acc[mt][nt], 0, 0, 0);

    const int rbase = (lane >> 4) * 4;
    #pragma unroll
    for (int mt = 0; mt < 2; ++mt) {
        #pragma unroll
        for (int nt = 0; nt < 4; ++nt) {
            #pragma unroll
            for (int r = 0; r < 4; ++r) {
                const int row = r0 + w * 32 + mt * 16 + rbase + r;
                const int col = nt * 16 + fm;
                out[(size_t)row * 64 + col] = 0.125f * acc[mt][nt][r];
            }
        }
    }
}

extern "C" void kernel_launch(void* const* d_in, const int* in_sizes, int n_in,
                              void* d_out, int out_size, void* d_ws, size_t ws_size,
                              hipStream_t stream)
{
    const float* x  = (const float*)d_in[0];
    const float* Wq = (const float*)d_in[1];
    const float* bq = (const float*)d_in[2];
    const float* Wk = (const float*)d_in[3];
    const float* bk = (const float*)d_in[4];
    const float* Wv = (const float*)d_in[5];
    const float* bv = (const float*)d_in[6];
    float* wsf = (float*)d_ws;
    unsigned short* wsu = (unsigned short*)d_ws;
    float* out = (float*)d_out;

    dim3 gCvt(512, 7);
    cvt_bf16<<<gCvt, 256, 0, stream>>>(x, Wq, Wk, Wv, wsu + XB_U);

    qkvkt768<<<768, 256, 0, stream>>>(wsu + XB_U, wsu + WB_U,
                                      bq, bk, bv, wsu, wsf + P_F);

    qT_fused<<<512, 256, 0, stream>>>(wsu, wsf + P_F, out);
}